// Round 14
// baseline (97.813 us; speedup 1.0000x reference)
//
#include <hip/hip_runtime.h>
#include <math.h>

#define NS 24

typedef float v2f __attribute__((ext_vector_type(2)));
typedef float v4f __attribute__((ext_vector_type(4)));

// ws layout (SoA): float partials[5][B] rows = {sp2, st2, spt, mp, mt}

// compile-time table of circle pixels: entries 0..194 in-grid (Voronoi),
// entry 195 = padding pixel (16,24) with label 0. Encoded (yy<<8)|x, yy=y-8.
struct PixTab { unsigned short v[196]; };
__device__ constexpr PixTab make_pix() {
    PixTab t{};
    int n = 0;
    const int w[16] = {0,3,5,6,6,7,7,7,8,7,7,7,6,6,5,3};
    for (int yy = 0; yy < 16; ++yy)
        for (int x = 16 - w[yy]; x <= 16 + w[yy]; ++x)
            if (x < 24) { t.v[n] = (unsigned short)((yy << 8) | x); n = n + 1; }
    t.v[195] = (unsigned short)((8 << 8) | 24);
    return t;
}
__device__ constexpr PixTab PIX = make_pix();

// non-circle e2f slots (xi<=16) to zero -- disjoint from Voronoi writes (no race)
struct ZTab { unsigned short v[76]; };
__device__ constexpr ZTab make_ztab() {
    ZTab z{};
    bool mark[16][17] = {};
    const int w[16] = {0,3,5,6,6,7,7,7,8,7,7,7,6,6,5,3};
    for (int yy = 0; yy < 16; ++yy)
        for (int x = 16 - w[yy]; x <= 16 + w[yy]; ++x)
            if (x < 24) mark[yy][x - 8] = true;
    mark[8][16] = true;   // pad pixel (16,24)
    int n = 0;
    for (int yy = 0; yy < 16; ++yy)
        for (int xi = 0; xi < 17; ++xi)
            if (!mark[yy][xi]) { z.v[n] = (unsigned short)(yy * 18 + xi); n = n + 1; }
    return z;
}
__device__ constexpr ZTab ZT = make_ztab();

// ---- compile-time twiddle tables (copied to LDS per block; exact 32nd roots) ----
constexpr float twc_(int p) {
    const float C[17] = {
        1.0f, 0.98078528040323044913f, 0.92387953251128675613f, 0.83146961230254523708f,
        0.70710678118654752440f, 0.55557023301960222474f, 0.38268343236508977173f,
        0.19509032201612826785f, 0.0f,
        -0.19509032201612826785f, -0.38268343236508977173f, -0.55557023301960222474f,
        -0.70710678118654752440f, -0.83146961230254523708f, -0.92387953251128675613f,
        -0.98078528040323044913f, -1.0f };
    return (p <= 16) ? C[p] : C[32 - p];
}
constexpr float tws_(int p) {
    const float S[17] = {
        0.0f, 0.19509032201612826785f, 0.38268343236508977173f, 0.55557023301960222474f,
        0.70710678118654752440f, 0.83146961230254523708f, 0.92387953251128675613f,
        0.98078528040323044913f, 1.0f,
        0.98078528040323044913f, 0.92387953251128675613f, 0.83146961230254523708f,
        0.70710678118654752440f, 0.55557023301960222474f, 0.38268343236508977173f,
        0.19509032201612826785f, 0.0f };
    return (p <= 16) ? -S[p] : S[32 - p];
}
// TW1G[l0][xi] = e^{-2pi i l0 (xi+8)/32}, l0 in [0,8), xi in [0,17), stride 18 cplx
struct alignas(16) TW1T { float v[8 * 18 * 2]; };
__device__ constexpr TW1T make_tw1() {
    TW1T t{};
    for (int l0 = 0; l0 < 8; ++l0)
        for (int xi = 0; xi < 17; ++xi) {
            int p = (l0 * (xi + 8)) & 31;
            t.v[(l0 * 18 + xi) * 2 + 0] = twc_(p);
            t.v[(l0 * 18 + xi) * 2 + 1] = tws_(p);
        }
    return t;
}
__device__ constexpr TW1T TW1G = make_tw1();
// TW2G[k0][yp] = e^{-2pi i k0 (yp+8)/32}, k0 in [0,4), yp in [0,16), stride 18 cplx
struct alignas(16) TW2T { float v[4 * 18 * 2]; };
__device__ constexpr TW2T make_tw2() {
    TW2T t{};
    for (int k0 = 0; k0 < 4; ++k0)
        for (int yp = 0; yp < 16; ++yp) {
            int p = (k0 * (yp + 8)) & 31;
            t.v[(k0 * 18 + yp) * 2 + 0] = twc_(p);
            t.v[(k0 * 18 + yp) * 2 + 1] = tws_(p);
        }
    return t;
}
__device__ constexpr TW2T TW2G = make_tw2();

// packed complex mul with w = (c, s)
static __device__ __forceinline__ v2f cmul(v2f e, v2f w) {
    v2f m = (v2f){e.y, e.y} * (v2f){w.y, w.x};
    return __builtin_elementwise_fma((v2f){e.x, e.x}, w, (v2f){-m.x, m.y});
}
static __device__ __forceinline__ float mag(v2f h) {
    v2f q = h * h;
    return sqrtf(q.x + q.y);
}

// DPP wave reduce (VALU pipe). dpp_ctrl must be a constant -> template param.
template <int CTRL>
static __device__ __forceinline__ float dpp_step(float x) {
    int y = __builtin_amdgcn_update_dpp(0, __float_as_int(x), CTRL, 0xf, 0xf, true);
    return __int_as_float(y);
}
static __device__ __forceinline__ float wave_sum(float x) {
    x += dpp_step<0x111>(x);  // row_shr:1
    x += dpp_step<0x112>(x);  // row_shr:2
    x += dpp_step<0x114>(x);  // row_shr:4
    x += dpp_step<0x118>(x);  // row_shr:8
    x += dpp_step<0x142>(x);  // row_bcast:15
    x += dpp_step<0x143>(x);  // row_bcast:31
    return x;                 // lane 63 holds the wave total
}
static __device__ __forceinline__ float wave_max(float x) {
    x = fmaxf(x, dpp_step<0x111>(x));
    x = fmaxf(x, dpp_step<0x112>(x));
    x = fmaxf(x, dpp_step<0x114>(x));
    x = fmaxf(x, dpp_step<0x118>(x));
    x = fmaxf(x, dpp_step<0x142>(x));
    x = fmaxf(x, dpp_step<0x143>(x));
    return x;
}

__global__ __launch_bounds__(256)
void loss_main(const float* __restrict__ output, const float* __restrict__ targets,
               float* __restrict__ partials, int B) {
    __shared__ float2 e24s;                           // phasor(sp[0]) - 1
    __shared__ __align__(16) float gx[NS * 32];       // gaussian x-factors (amp folded in)
    __shared__ __align__(16) float gyT[32 * 24];      // gaussian y-factors, [r][s], stride 24
    __shared__ __align__(16) float e2f[16 * 18 * 2];  // e = phasor-1, [yy][x-8], stride 18 cplx
    __shared__ __align__(16) float tw2f[4 * 36];      // stage-2 twiddles, stride 18 cplx
    __shared__ __align__(16) float gT2f[32 * 36];     // stage-1 out [l][yp] cplx, stride 18 cplx
    __shared__ __align__(16) char uA[5120];           // union: tw1 (1152B) then pm (5120B)

    float* tw1f = (float*)uA;  // stage-1 twiddles [l0][xi], stride 18 cplx -- dead after stage 1
    float* pmf  = (float*)uA;  // |pred| fftshifted, stride 40 -- written in stage 2

    const int b = blockIdx.x;
    const int t = threadIdx.x;
    const float* so = output + b * NS * 3;    // block-uniform seeds (scalar loads)
    const float* tg = targets + b * NS * 3;

    // ================= PHASE A (single barrier interval, no internal deps) ======
    if (t == 0) {
        float sv0, cv0;
        __sincosf(6.2831853071795864f * so[2], &sv0, &cv0);
        e24s = make_float2(cv0 - 1.0f, sv0);
    }
    // twiddle copy: 108 v4f (72 tw1, 36 tw2)
    if (t < 108) {
        if (t < 72) *(v4f*)&tw1f[t * 4] = *(const v4f*)&TW1G.v[t * 4];
        else        *(v4f*)&tw2f[(t - 72) * 4] = *(const v4f*)&TW2G.v[(t - 72) * 4];
    }
    // gaussian tables straight from global (broadcast loads; no LDS staging/barrier)
    for (int idx = t; idx < NS * 32; idx += 256) {
        int s = idx >> 5, c = idx & 31;
        float dx = (float)c - tg[3 * s];
        gx[idx] = tg[3 * s + 2] * __expf(dx * dx * (-1.0f / 4.5f));
    }
    for (int idx = t; idx < 32 * 24; idx += 256) {
        int r = idx / 24, s = idx - r * 24;
        float dy = (float)r - tg[3 * s + 1];
        gyT[idx] = __expf(dy * dy * (-1.0f / 4.5f));
    }
    // packed-pair Voronoi (threads 0..97, 2 px each) + non-circle zeroing (98..173)
    if (t < 98) {
        int pv0 = PIX.v[t], pv1 = PIX.v[t + 98];
        int yy0 = pv0 >> 8, x0 = (pv0 & 255) - 8;
        int yy1 = pv1 >> 8, x1 = (pv1 & 255) - 8;
        v2f FI = {(float)yy0, (float)yy1};
        v2f FJ = {(float)x0, (float)x1};
        v2f bd = {1e30f, 1e30f};
        v2f bph = {0.f, 0.f};
#pragma unroll
        for (int s = 0; s < NS; ++s) {
            float sx = so[3 * s], sy = so[3 * s + 1], phs = so[3 * s + 2];
            v2f dX = FI - (v2f){sx, sx};
            v2f dY = FJ - (v2f){sy, sy};
            v2f d2 = __builtin_elementwise_fma(dX, dX, dY * dY);
            if (d2.x < bd.x) { bd.x = d2.x; bph.x = phs; }  // strict <: first-min tie
            if (d2.y < bd.y) { bd.y = d2.y; bph.y = phs; }
        }
        float ph1 = (t == 97) ? so[2] : bph.y;  // pixel 195 = padding (16,24): label 0
        float sv0, cv0, sv1, cv1;
        __sincosf(6.2831853071795864f * bph.x, &sv0, &cv0);
        __sincosf(6.2831853071795864f * ph1, &sv1, &cv1);
        *(v2f*)&e2f[(yy0 * 18 + x0) * 2] = (v2f){cv0 - 1.0f, sv0};
        *(v2f*)&e2f[(yy1 * 18 + x1) * 2] = (v2f){cv1 - 1.0f, sv1};
    } else if (t < 98 + 76) {
        int idx = (int)ZT.v[t - 98];
        *(v2f*)&e2f[idx * 2] = (v2f){0.f, 0.f};
    }
    __syncthreads();   // barrier 1 of 3

    // ---- stage 1: radix-4 row DFT over x=8..24. 128 threads, 4 outputs each ----
    if (t < 128) {
        int yy = t >> 3, l0 = t & 7;
        const float* row = &e2f[yy * 36];        // xi = 0 -> x = 8
        const float* twr = &tw1f[l0 * 36];
        v2f c0 = {0,0}, c1 = {0,0}, c2 = {0,0}, c3 = {0,0};
#pragma unroll
        for (int q = 0; q < 8; ++q) {
            v4f e4 = *(const v4f*)&row[q * 4];   // cplx xi=2q, 2q+1
            v4f w4 = *(const v4f*)&twr[q * 4];
            v2f ca = cmul((v2f){e4.x, e4.y}, (v2f){w4.x, w4.y});  // m = 2q mod 4
            v2f cb = cmul((v2f){e4.z, e4.w}, (v2f){w4.z, w4.w});  // m = 2q+1 mod 4
            if ((q & 1) == 0) { c0 += ca; c1 += cb; }
            else              { c2 += ca; c3 += cb; }
        }
        {   // tail xi=16 (x=24), m=0
            v2f e16 = *(const v2f*)&row[32];
            v2f w16 = *(const v2f*)&twr[32];
            c0 += cmul(e16, w16);
        }
        v2f a = c0 + c2, bb = c0 - c2;
        v2f cc = c1 + c3, d = c1 - c3;
        v2f du = {d.y, -d.x};   // -i * d
        *(v2f*)&gT2f[l0 * 36 + yy * 2]        = a + cc;
        *(v2f*)&gT2f[(l0 + 8) * 36 + yy * 2]  = bb + du;
        *(v2f*)&gT2f[(l0 + 16) * 36 + yy * 2] = a - cc;
        *(v2f*)&gT2f[(l0 + 24) * 36 + yy * 2] = bb - du;
    }
    __syncthreads();   // barrier 2 of 3

    // ---- stage 2: radix-8 col DFT over y=8..23. 128 threads, 8 outputs each ----
    if (t < 128) {
        int l = t >> 2, k0 = t & 3;
        const float* gTr = &gT2f[l * 36];
        const float* twr = &tw2f[k0 * 36];
        v2f c[8];
#pragma unroll
        for (int q = 0; q < 4; ++q) {
            v4f glo = *(const v4f*)&gTr[q * 4];        // yp = 2q, 2q+1
            v4f ghi = *(const v4f*)&gTr[q * 4 + 16];   // yp = 2q+8, 2q+9
            v4f wlo = *(const v4f*)&twr[q * 4];
            v4f whi = *(const v4f*)&twr[q * 4 + 16];
            c[2 * q]     = cmul((v2f){glo.x, glo.y}, (v2f){wlo.x, wlo.y})
                         + cmul((v2f){ghi.x, ghi.y}, (v2f){whi.x, whi.y});
            c[2 * q + 1] = cmul((v2f){glo.z, glo.w}, (v2f){wlo.z, wlo.w})
                         + cmul((v2f){ghi.z, ghi.w}, (v2f){whi.z, whi.w});
        }
        v2f Ea = c[0] + c[4], Eb = c[0] - c[4];
        v2f Ec = c[2] + c[6], Ed = c[2] - c[6];
        v2f Edu = {Ed.y, -Ed.x};
        v2f E0 = Ea + Ec, E1 = Eb + Edu, E2 = Ea - Ec, E3 = Eb - Edu;
        v2f Oa = c[1] + c[5], Ob = c[1] - c[5];
        v2f Oc = c[3] + c[7], Od = c[3] - c[7];
        v2f Odu = {Od.y, -Od.x};
        v2f O0 = Oa + Oc, O1 = Ob + Odu, O2 = Oa - Oc, O3 = Ob - Odu;
        const float s2 = 0.70710678118654752440f;
        v2f w1O = (v2f){s2, s2} * (v2f){O1.x + O1.y, O1.y - O1.x};     // w * O1
        v2f w3O = (v2f){s2, s2} * (v2f){O3.y - O3.x, -(O3.x + O3.y)};  // w^3 * O3
        v2f miO = {O2.y, -O2.x};                                       // -i * O2
        {   // analytic pixel (24,16): e24 * (-1)^l * i^k0 (same for all 8 j)
            float2 e24 = e24s;
            float ar2 = (k0 == 0) ? 1.f : (k0 == 2) ? -1.f : 0.f;  // i^k0
            float ai2 = (k0 == 1) ? 1.f : (k0 == 3) ? -1.f : 0.f;
            float sgn = (l & 1) ? -1.f : 1.f;
            v2f T = {sgn * (e24.x * ar2 - e24.y * ai2),
                     sgn * (e24.x * ai2 + e24.y * ar2)};
            E0 += T; E1 += T; E2 += T; E3 += T;   // fold into E (appears in every H)
        }
        v2f h0 = E0 + O0;
        if (t == 0) h0.x += 1024.0f;   // FFT(ones) delta at (k,l)=(0,0)
        int v = (l + 16) & 31;
        pmf[(k0 + 16) * 40 + v] = mag(h0);          // k = k0
        pmf[(k0 + 20) * 40 + v] = mag(E1 + w1O);    // k = k0+4
        pmf[(k0 + 24) * 40 + v] = mag(E2 + miO);    // k = k0+8
        pmf[(k0 + 28) * 40 + v] = mag(E3 + w3O);    // k = k0+12
        pmf[(k0)      * 40 + v] = mag(E0 - O0);     // k = k0+16
        pmf[(k0 + 4)  * 40 + v] = mag(E1 - w1O);    // k = k0+20
        pmf[(k0 + 8)  * 40 + v] = mag(E2 - miO);    // k = k0+24
        pmf[(k0 + 12) * 40 + v] = mag(E3 - w3O);    // k = k0+28
    }
    __syncthreads();   // barrier 3 of 3

    // ---- target + reductions: 64 threads x 16 px (rows rr+8k share gx); whole
    // block total lives in wave 0 -> single DPP reduce, NO final barrier ----
    if (t < 64) {
        int rr = t >> 3;              // 0..7
        int c0i = (t & 7) * 4;
        v2f a01[4] = {{0,0},{0,0},{0,0},{0,0}};
        v2f a23[4] = {{0,0},{0,0},{0,0},{0,0}};
#pragma unroll
        for (int q = 0; q < 6; ++q) {
            v4f gy0 = *(const v4f*)&gyT[rr * 24 + q * 4];
            v4f gy1 = *(const v4f*)&gyT[(rr + 8) * 24 + q * 4];
            v4f gy2 = *(const v4f*)&gyT[(rr + 16) * 24 + q * 4];
            v4f gy3 = *(const v4f*)&gyT[(rr + 24) * 24 + q * 4];
#pragma unroll
            for (int j = 0; j < 4; ++j) {
                v4f g4 = *(const v4f*)&gx[(4 * q + j) * 32 + c0i];
                float g0 = (j == 0) ? gy0.x : (j == 1) ? gy0.y : (j == 2) ? gy0.z : gy0.w;
                float g1 = (j == 0) ? gy1.x : (j == 1) ? gy1.y : (j == 2) ? gy1.z : gy1.w;
                float g2 = (j == 0) ? gy2.x : (j == 1) ? gy2.y : (j == 2) ? gy2.z : gy2.w;
                float g3 = (j == 0) ? gy3.x : (j == 1) ? gy3.y : (j == 2) ? gy3.z : gy3.w;
                v2f glo = {g4.x, g4.y}, ghi = {g4.z, g4.w};
                a01[0] = __builtin_elementwise_fma((v2f){g0, g0}, glo, a01[0]);
                a23[0] = __builtin_elementwise_fma((v2f){g0, g0}, ghi, a23[0]);
                a01[1] = __builtin_elementwise_fma((v2f){g1, g1}, glo, a01[1]);
                a23[1] = __builtin_elementwise_fma((v2f){g1, g1}, ghi, a23[1]);
                a01[2] = __builtin_elementwise_fma((v2f){g2, g2}, glo, a01[2]);
                a23[2] = __builtin_elementwise_fma((v2f){g2, g2}, ghi, a23[2]);
                a01[3] = __builtin_elementwise_fma((v2f){g3, g3}, glo, a01[3]);
                a23[3] = __builtin_elementwise_fma((v2f){g3, g3}, ghi, a23[3]);
            }
        }
        float sp2 = 0.f, st2 = 0.f, spt = 0.f, mp = 0.f, mt = 0.f;
#pragma unroll
        for (int k = 0; k < 4; ++k) {
            v4f p4 = *(const v4f*)&pmf[(rr + 8 * k) * 40 + c0i];
            v2f p01 = {p4.x, p4.y}, p23 = {p4.z, p4.w};
            v2f s2v = __builtin_elementwise_fma(p23, p23, p01 * p01);
            v2f t2v = __builtin_elementwise_fma(a23[k], a23[k], a01[k] * a01[k]);
            v2f ptv = __builtin_elementwise_fma(p23, a23[k], p01 * a01[k]);
            sp2 += s2v.x + s2v.y;
            st2 += t2v.x + t2v.y;
            spt += ptv.x + ptv.y;
            mp = fmaxf(mp, fmaxf(fmaxf(p4.x, p4.y), fmaxf(p4.z, p4.w)));
            v2f tm = __builtin_elementwise_max(a01[k], a23[k]);
            mt = fmaxf(mt, fmaxf(tm.x, tm.y));
        }
        sp2 = wave_sum(sp2);
        st2 = wave_sum(st2);
        spt = wave_sum(spt);
        mp  = wave_max(mp);
        mt  = wave_max(mt);
        if (t == 63) {
            // plain stores -- NO atomics, NO fences (round-4 lesson: contended
            // same-line device atomics serialize at ~12ns each).
            partials[0 * B + b] = sp2;
            partials[1 * B + b] = st2;
            partials[2 * B + b] = spt;
            partials[3 * B + b] = mp;
            partials[4 * B + b] = mt;
        }
    }
}

__global__ __launch_bounds__(1024)
void finalize_loss(const float* __restrict__ partials, float* __restrict__ out, int B) {
    __shared__ double reds[16][3];
    __shared__ float redx[16][2];
    const int t = threadIdx.x;
    double sp2 = 0.0, st2 = 0.0, spt = 0.0;
    float mp = 0.f, mt = 0.f;
    for (int i = t; i < B; i += 1024) {
        sp2 += (double)partials[0 * B + i];
        st2 += (double)partials[1 * B + i];
        spt += (double)partials[2 * B + i];
        mp = fmaxf(mp, partials[3 * B + i]);
        mt = fmaxf(mt, partials[4 * B + i]);
    }
    for (int off = 32; off > 0; off >>= 1) {
        sp2 += __shfl_down(sp2, off);
        st2 += __shfl_down(st2, off);
        spt += __shfl_down(spt, off);
        mp = fmaxf(mp, __shfl_down(mp, off));
        mt = fmaxf(mt, __shfl_down(mt, off));
    }
    int wave = t >> 6, lane = t & 63;
    if (lane == 0) {
        reds[wave][0] = sp2; reds[wave][1] = st2; reds[wave][2] = spt;
        redx[wave][0] = mp;  redx[wave][1] = mt;
    }
    __syncthreads();
    if (t == 0) {
        for (int w = 1; w < 16; ++w) {
            sp2 += reds[w][0];
            st2 += reds[w][1];
            spt += reds[w][2];
            mp = fmaxf(mp, redx[w][0]);
            mt = fmaxf(mt, redx[w][1]);
        }
        double Mp = (double)mp, Mt = (double)mt;
        double loss = (sp2 * (Mt / Mp) + st2 * (Mp / Mt) - 2.0 * spt) / sqrt(sp2 * st2);
        out[0] = (float)loss;
    }
}

extern "C" void kernel_launch(void* const* d_in, const int* in_sizes, int n_in,
                              void* d_out, int out_size, void* d_ws, size_t ws_size,
                              hipStream_t stream) {
    const float* output  = (const float*)d_in[0];
    const float* targets = (const float*)d_in[1];
    int B = in_sizes[0] / (NS * 3);
    float* partials = (float*)d_ws;     // 5*B floats

    loss_main<<<B, 256, 0, stream>>>(output, targets, partials, B);
    finalize_loss<<<1, 1024, 0, stream>>>(partials, (float*)d_out, B);
}

// Round 15
// 95.198 us; speedup vs baseline: 1.0275x; 1.0275x over previous
//
#include <hip/hip_runtime.h>
#include <math.h>

#define NS 24

typedef float v2f __attribute__((ext_vector_type(2)));
typedef float v4f __attribute__((ext_vector_type(4)));

// ws layout (SoA): float partials[5][B] rows = {sp2, st2, spt, mp, mt}

// compile-time table of circle pixels: entries 0..194 in-grid (Voronoi),
// entry 195 = padding pixel (16,24) with label 0. Encoded (yy<<8)|x, yy=y-8.
struct PixTab { unsigned short v[196]; };
__device__ constexpr PixTab make_pix() {
    PixTab t{};
    int n = 0;
    const int w[16] = {0,3,5,6,6,7,7,7,8,7,7,7,6,6,5,3};
    for (int yy = 0; yy < 16; ++yy)
        for (int x = 16 - w[yy]; x <= 16 + w[yy]; ++x)
            if (x < 24) { t.v[n] = (unsigned short)((yy << 8) | x); n = n + 1; }
    t.v[195] = (unsigned short)((8 << 8) | 24);
    return t;
}
__device__ constexpr PixTab PIX = make_pix();

// non-circle e2f slots (xi<=16) to zero -- disjoint from Voronoi writes (no race)
struct ZTab { unsigned short v[76]; };
__device__ constexpr ZTab make_ztab() {
    ZTab z{};
    bool mark[16][17] = {};
    const int w[16] = {0,3,5,6,6,7,7,7,8,7,7,7,6,6,5,3};
    for (int yy = 0; yy < 16; ++yy)
        for (int x = 16 - w[yy]; x <= 16 + w[yy]; ++x)
            if (x < 24) mark[yy][x - 8] = true;
    mark[8][16] = true;   // pad pixel (16,24)
    int n = 0;
    for (int yy = 0; yy < 16; ++yy)
        for (int xi = 0; xi < 17; ++xi)
            if (!mark[yy][xi]) { z.v[n] = (unsigned short)(yy * 18 + xi); n = n + 1; }
    return z;
}
__device__ constexpr ZTab ZT = make_ztab();

// ---- compile-time twiddle tables (copied to LDS per block; exact 32nd roots) ----
constexpr float twc_(int p) {
    const float C[17] = {
        1.0f, 0.98078528040323044913f, 0.92387953251128675613f, 0.83146961230254523708f,
        0.70710678118654752440f, 0.55557023301960222474f, 0.38268343236508977173f,
        0.19509032201612826785f, 0.0f,
        -0.19509032201612826785f, -0.38268343236508977173f, -0.55557023301960222474f,
        -0.70710678118654752440f, -0.83146961230254523708f, -0.92387953251128675613f,
        -0.98078528040323044913f, -1.0f };
    return (p <= 16) ? C[p] : C[32 - p];
}
constexpr float tws_(int p) {
    const float S[17] = {
        0.0f, 0.19509032201612826785f, 0.38268343236508977173f, 0.55557023301960222474f,
        0.70710678118654752440f, 0.83146961230254523708f, 0.92387953251128675613f,
        0.98078528040323044913f, 1.0f,
        0.98078528040323044913f, 0.92387953251128675613f, 0.83146961230254523708f,
        0.70710678118654752440f, 0.55557023301960222474f, 0.38268343236508977173f,
        0.19509032201612826785f, 0.0f };
    return (p <= 16) ? -S[p] : S[32 - p];
}
// TW1G[l0][xi] = e^{-2pi i l0 (xi+8)/32}, l0 in [0,8), xi in [0,17), stride 18 cplx
struct alignas(16) TW1T { float v[8 * 18 * 2]; };
__device__ constexpr TW1T make_tw1() {
    TW1T t{};
    for (int l0 = 0; l0 < 8; ++l0)
        for (int xi = 0; xi < 17; ++xi) {
            int p = (l0 * (xi + 8)) & 31;
            t.v[(l0 * 18 + xi) * 2 + 0] = twc_(p);
            t.v[(l0 * 18 + xi) * 2 + 1] = tws_(p);
        }
    return t;
}
__device__ constexpr TW1T TW1G = make_tw1();
// TW2G[k0][yp] = e^{-2pi i k0 (yp+8)/32}, k0 in [0,4), yp in [0,16), stride 18 cplx
struct alignas(16) TW2T { float v[4 * 18 * 2]; };
__device__ constexpr TW2T make_tw2() {
    TW2T t{};
    for (int k0 = 0; k0 < 4; ++k0)
        for (int yp = 0; yp < 16; ++yp) {
            int p = (k0 * (yp + 8)) & 31;
            t.v[(k0 * 18 + yp) * 2 + 0] = twc_(p);
            t.v[(k0 * 18 + yp) * 2 + 1] = tws_(p);
        }
    return t;
}
__device__ constexpr TW2T TW2G = make_tw2();

// packed complex mul with w = (c, s)
static __device__ __forceinline__ v2f cmul(v2f e, v2f w) {
    v2f m = (v2f){e.y, e.y} * (v2f){w.y, w.x};
    return __builtin_elementwise_fma((v2f){e.x, e.x}, w, (v2f){-m.x, m.y});
}
static __device__ __forceinline__ float mag(v2f h) {
    v2f q = h * h;
    return sqrtf(q.x + q.y);
}

// DPP wave reduce (VALU pipe). dpp_ctrl must be a constant -> template param.
template <int CTRL>
static __device__ __forceinline__ float dpp_step(float x) {
    int y = __builtin_amdgcn_update_dpp(0, __float_as_int(x), CTRL, 0xf, 0xf, true);
    return __int_as_float(y);
}
static __device__ __forceinline__ float wave_sum(float x) {
    x += dpp_step<0x111>(x);  // row_shr:1
    x += dpp_step<0x112>(x);  // row_shr:2
    x += dpp_step<0x114>(x);  // row_shr:4
    x += dpp_step<0x118>(x);  // row_shr:8
    x += dpp_step<0x142>(x);  // row_bcast:15
    x += dpp_step<0x143>(x);  // row_bcast:31
    return x;                 // lane 63 holds the wave total
}
static __device__ __forceinline__ float wave_max(float x) {
    x = fmaxf(x, dpp_step<0x111>(x));
    x = fmaxf(x, dpp_step<0x112>(x));
    x = fmaxf(x, dpp_step<0x114>(x));
    x = fmaxf(x, dpp_step<0x118>(x));
    x = fmaxf(x, dpp_step<0x142>(x));
    x = fmaxf(x, dpp_step<0x143>(x));
    return x;
}

__global__ __launch_bounds__(256)
void loss_main(const float* __restrict__ output, const float* __restrict__ targets,
               float* __restrict__ partials, int B) {
    __shared__ float2 e24s;                           // phasor(sp[0]) - 1
    __shared__ __align__(16) float gx[NS * 32];       // gaussian x-factors (amp folded in)
    __shared__ __align__(16) float gyT[32 * 24];      // gaussian y-factors, [r][s], stride 24
    __shared__ __align__(16) float e2f[16 * 18 * 2];  // e = phasor-1, [yy][x-8], stride 18 cplx
    __shared__ __align__(16) float tw2f[4 * 36];      // stage-2 twiddles, stride 18 cplx
    __shared__ __align__(16) float gT2f[32 * 36];     // stage-1 out [l][yp] cplx, stride 18 cplx
    __shared__ __align__(16) char uA[5120];           // union: tw1 (1152B) then pm (5120B)
    __shared__ float redm[2][5];

    float* tw1f = (float*)uA;  // stage-1 twiddles [l0][xi] -- dead after stage 1
    float* pmf  = (float*)uA;  // |pred| fftshifted, stride 40 -- written in stage 2

    const int b = blockIdx.x;
    const int t = threadIdx.x;
    const float* so = output + b * NS * 3;    // block-uniform seeds (scalar loads)
    const float* tg = targets + b * NS * 3;

    // ================= PHASE A (all 256 threads, one barrier interval) =========
    if (t == 0) {
        float sv0, cv0;
        __sincosf(6.2831853071795864f * so[2], &sv0, &cv0);
        e24s = make_float2(cv0 - 1.0f, sv0);
    }
    // twiddle copy: 108 v4f (72 tw1, 36 tw2)
    if (t < 108) {
        if (t < 72) *(v4f*)&tw1f[t * 4] = *(const v4f*)&TW1G.v[t * 4];
        else        *(v4f*)&tw2f[(t - 72) * 4] = *(const v4f*)&TW2G.v[(t - 72) * 4];
    }
    // gaussian tables straight from global (broadcast loads)
    for (int idx = t; idx < NS * 32; idx += 256) {
        int s = idx >> 5, c = idx & 31;
        float dx = (float)c - tg[3 * s];
        gx[idx] = tg[3 * s + 2] * __expf(dx * dx * (-1.0f / 4.5f));
    }
    for (int idx = t; idx < 32 * 24; idx += 256) {
        int r = idx / 24, s = idx - r * 24;
        float dy = (float)r - tg[3 * s + 1];
        gyT[idx] = __expf(dy * dy * (-1.0f / 4.5f));
    }
    // packed-pair Voronoi (threads 0..97, 2 px each) + non-circle zeroing (98..173)
    if (t < 98) {
        int pv0 = PIX.v[t], pv1 = PIX.v[t + 98];
        int yy0 = pv0 >> 8, x0 = (pv0 & 255) - 8;
        int yy1 = pv1 >> 8, x1 = (pv1 & 255) - 8;
        v2f FI = {(float)yy0, (float)yy1};
        v2f FJ = {(float)x0, (float)x1};
        v2f bd = {1e30f, 1e30f};
        v2f bph = {0.f, 0.f};
#pragma unroll
        for (int s = 0; s < NS; ++s) {
            float sx = so[3 * s], sy = so[3 * s + 1], phs = so[3 * s + 2];
            v2f dX = FI - (v2f){sx, sx};
            v2f dY = FJ - (v2f){sy, sy};
            v2f d2 = __builtin_elementwise_fma(dX, dX, dY * dY);
            if (d2.x < bd.x) { bd.x = d2.x; bph.x = phs; }  // strict <: first-min tie
            if (d2.y < bd.y) { bd.y = d2.y; bph.y = phs; }
        }
        float ph1 = (t == 97) ? so[2] : bph.y;  // pixel 195 = padding (16,24): label 0
        float sv0, cv0, sv1, cv1;
        __sincosf(6.2831853071795864f * bph.x, &sv0, &cv0);
        __sincosf(6.2831853071795864f * ph1, &sv1, &cv1);
        *(v2f*)&e2f[(yy0 * 18 + x0) * 2] = (v2f){cv0 - 1.0f, sv0};
        *(v2f*)&e2f[(yy1 * 18 + x1) * 2] = (v2f){cv1 - 1.0f, sv1};
    } else if (t < 98 + 76) {
        int idx = (int)ZT.v[t - 98];
        *(v2f*)&e2f[idx * 2] = (v2f){0.f, 0.f};
    }
    __syncthreads();   // barrier 1 of 4

    // ========= WAVE SPECIALIZATION: waves 0-1 = DFT, waves 2-3 = target-gen ====
    // target accumulators (waves 2-3) persist in registers across barriers
    v2f ta01 = {0,0}, ta23 = {0,0}, tb01 = {0,0}, tb23 = {0,0};

    if (t < 128) {
        // ---- stage 1: radix-4 row DFT over x=8..24. 4 outputs each ----
        int yy = t >> 3, l0 = t & 7;
        const float* row = &e2f[yy * 36];        // xi = 0 -> x = 8
        const float* twr = &tw1f[l0 * 36];
        v2f c0 = {0,0}, c1 = {0,0}, c2 = {0,0}, c3 = {0,0};
#pragma unroll
        for (int q = 0; q < 8; ++q) {
            v4f e4 = *(const v4f*)&row[q * 4];   // cplx xi=2q, 2q+1
            v4f w4 = *(const v4f*)&twr[q * 4];
            v2f ca = cmul((v2f){e4.x, e4.y}, (v2f){w4.x, w4.y});  // m = 2q mod 4
            v2f cb = cmul((v2f){e4.z, e4.w}, (v2f){w4.z, w4.w});  // m = 2q+1 mod 4
            if ((q & 1) == 0) { c0 += ca; c1 += cb; }
            else              { c2 += ca; c3 += cb; }
        }
        {   // tail xi=16 (x=24), m=0
            v2f e16 = *(const v2f*)&row[32];
            v2f w16 = *(const v2f*)&twr[32];
            c0 += cmul(e16, w16);
        }
        v2f a = c0 + c2, bb = c0 - c2;
        v2f cc = c1 + c3, d = c1 - c3;
        v2f du = {d.y, -d.x};   // -i * d
        *(v2f*)&gT2f[l0 * 36 + yy * 2]        = a + cc;
        *(v2f*)&gT2f[(l0 + 8) * 36 + yy * 2]  = bb + du;
        *(v2f*)&gT2f[(l0 + 16) * 36 + yy * 2] = a - cc;
        *(v2f*)&gT2f[(l0 + 24) * 36 + yy * 2] = bb - du;
    } else {
        // ---- target-gen: 128 threads x 8 px (rows r and r+16 share gx) ----
        int tid2 = t - 128;
        int r = tid2 >> 3;
        int c0i = (tid2 & 7) * 4;
#pragma unroll
        for (int q = 0; q < 6; ++q) {
            v4f gy4a = *(const v4f*)&gyT[r * 24 + q * 4];
            v4f gy4b = *(const v4f*)&gyT[(r + 16) * 24 + q * 4];
#pragma unroll
            for (int j = 0; j < 4; ++j) {
                v4f g4 = *(const v4f*)&gx[(4 * q + j) * 32 + c0i];
                float ga = (j == 0) ? gy4a.x : (j == 1) ? gy4a.y : (j == 2) ? gy4a.z : gy4a.w;
                float gb = (j == 0) ? gy4b.x : (j == 1) ? gy4b.y : (j == 2) ? gy4b.z : gy4b.w;
                v2f glo = {g4.x, g4.y}, ghi = {g4.z, g4.w};
                ta01 = __builtin_elementwise_fma((v2f){ga, ga}, glo, ta01);
                ta23 = __builtin_elementwise_fma((v2f){ga, ga}, ghi, ta23);
                tb01 = __builtin_elementwise_fma((v2f){gb, gb}, glo, tb01);
                tb23 = __builtin_elementwise_fma((v2f){gb, gb}, ghi, tb23);
            }
        }
    }
    __syncthreads();   // barrier 2 of 4

    // ---- stage 2 (waves 0-1): radix-8 col DFT, 8 outputs each; writes pmf ----
    if (t < 128) {
        int l = t >> 2, k0 = t & 3;
        const float* gTr = &gT2f[l * 36];
        const float* twr = &tw2f[k0 * 36];
        v2f c[8];
#pragma unroll
        for (int q = 0; q < 4; ++q) {
            v4f glo = *(const v4f*)&gTr[q * 4];        // yp = 2q, 2q+1
            v4f ghi = *(const v4f*)&gTr[q * 4 + 16];   // yp = 2q+8, 2q+9
            v4f wlo = *(const v4f*)&twr[q * 4];
            v4f whi = *(const v4f*)&twr[q * 4 + 16];
            c[2 * q]     = cmul((v2f){glo.x, glo.y}, (v2f){wlo.x, wlo.y})
                         + cmul((v2f){ghi.x, ghi.y}, (v2f){whi.x, whi.y});
            c[2 * q + 1] = cmul((v2f){glo.z, glo.w}, (v2f){wlo.z, wlo.w})
                         + cmul((v2f){ghi.z, ghi.w}, (v2f){whi.z, whi.w});
        }
        v2f Ea = c[0] + c[4], Eb = c[0] - c[4];
        v2f Ec = c[2] + c[6], Ed = c[2] - c[6];
        v2f Edu = {Ed.y, -Ed.x};
        v2f E0 = Ea + Ec, E1 = Eb + Edu, E2 = Ea - Ec, E3 = Eb - Edu;
        v2f Oa = c[1] + c[5], Ob = c[1] - c[5];
        v2f Oc = c[3] + c[7], Od = c[3] - c[7];
        v2f Odu = {Od.y, -Od.x};
        v2f O0 = Oa + Oc, O1 = Ob + Odu, O2 = Oa - Oc, O3 = Ob - Odu;
        const float s2 = 0.70710678118654752440f;
        v2f w1O = (v2f){s2, s2} * (v2f){O1.x + O1.y, O1.y - O1.x};     // w * O1
        v2f w3O = (v2f){s2, s2} * (v2f){O3.y - O3.x, -(O3.x + O3.y)};  // w^3 * O3
        v2f miO = {O2.y, -O2.x};                                       // -i * O2
        {   // analytic pixel (24,16): e24 * (-1)^l * i^k0 (same for all 8 j)
            float2 e24 = e24s;
            float ar2 = (k0 == 0) ? 1.f : (k0 == 2) ? -1.f : 0.f;  // i^k0
            float ai2 = (k0 == 1) ? 1.f : (k0 == 3) ? -1.f : 0.f;
            float sgn = (l & 1) ? -1.f : 1.f;
            v2f T = {sgn * (e24.x * ar2 - e24.y * ai2),
                     sgn * (e24.x * ai2 + e24.y * ar2)};
            E0 += T; E1 += T; E2 += T; E3 += T;   // fold into E (appears in every H)
        }
        v2f h0 = E0 + O0;
        if (t == 0) h0.x += 1024.0f;   // FFT(ones) delta at (k,l)=(0,0)
        int v = (l + 16) & 31;
        pmf[(k0 + 16) * 40 + v] = mag(h0);          // k = k0
        pmf[(k0 + 20) * 40 + v] = mag(E1 + w1O);    // k = k0+4
        pmf[(k0 + 24) * 40 + v] = mag(E2 + miO);    // k = k0+8
        pmf[(k0 + 28) * 40 + v] = mag(E3 + w3O);    // k = k0+12
        pmf[(k0)      * 40 + v] = mag(E0 - O0);     // k = k0+16
        pmf[(k0 + 4)  * 40 + v] = mag(E1 - w1O);    // k = k0+20
        pmf[(k0 + 8)  * 40 + v] = mag(E2 - miO);    // k = k0+24
        pmf[(k0 + 12) * 40 + v] = mag(E3 - w3O);    // k = k0+28
    }
    __syncthreads();   // barrier 3 of 4

    // ---- tail (waves 2-3): combine pm with registered target values ----
    if (t >= 128) {
        int tid2 = t - 128;
        int r = tid2 >> 3;
        int c0i = (tid2 & 7) * 4;
        v4f p4a = *(const v4f*)&pmf[r * 40 + c0i];
        v4f p4b = *(const v4f*)&pmf[(r + 16) * 40 + c0i];
        v2f pa01 = {p4a.x, p4a.y}, pa23 = {p4a.z, p4a.w};
        v2f pb01 = {p4b.x, p4b.y}, pb23 = {p4b.z, p4b.w};
        v2f s2v = pa01 * pa01 + pa23 * pa23 + pb01 * pb01 + pb23 * pb23;
        v2f t2v = ta01 * ta01 + ta23 * ta23 + tb01 * tb01 + tb23 * tb23;
        v2f ptv = pa01 * ta01 + pa23 * ta23 + pb01 * tb01 + pb23 * tb23;
        float sp2 = s2v.x + s2v.y;
        float st2 = t2v.x + t2v.y;
        float spt = ptv.x + ptv.y;
        float mp = fmaxf(fmaxf(fmaxf(p4a.x, p4a.y), fmaxf(p4a.z, p4a.w)),
                         fmaxf(fmaxf(p4b.x, p4b.y), fmaxf(p4b.z, p4b.w)));
        v2f tm = __builtin_elementwise_max(__builtin_elementwise_max(ta01, ta23),
                                           __builtin_elementwise_max(tb01, tb23));
        float mt = fmaxf(tm.x, tm.y);
        sp2 = wave_sum(sp2);
        st2 = wave_sum(st2);
        spt = wave_sum(spt);
        mp  = wave_max(mp);
        mt  = wave_max(mt);
        int wv = (t >> 6) - 2, lane = t & 63;
        if (lane == 63) {
            redm[wv][0] = sp2; redm[wv][1] = st2; redm[wv][2] = spt;
            redm[wv][3] = mp;  redm[wv][4] = mt;
        }
    }
    __syncthreads();   // barrier 4 of 4
    if (t == 0) {
        // plain stores -- NO atomics, NO fences (round-4 lesson: contended
        // same-line device atomics serialize at ~12ns each).
        partials[0 * B + b] = redm[0][0] + redm[1][0];
        partials[1 * B + b] = redm[0][1] + redm[1][1];
        partials[2 * B + b] = redm[0][2] + redm[1][2];
        partials[3 * B + b] = fmaxf(redm[0][3], redm[1][3]);
        partials[4 * B + b] = fmaxf(redm[0][4], redm[1][4]);
    }
}

__global__ __launch_bounds__(1024)
void finalize_loss(const float* __restrict__ partials, float* __restrict__ out, int B) {
    __shared__ double reds[16][3];
    __shared__ float redx[16][2];
    const int t = threadIdx.x;
    double sp2 = 0.0, st2 = 0.0, spt = 0.0;
    float mp = 0.f, mt = 0.f;
    for (int i = t; i < B; i += 1024) {
        sp2 += (double)partials[0 * B + i];
        st2 += (double)partials[1 * B + i];
        spt += (double)partials[2 * B + i];
        mp = fmaxf(mp, partials[3 * B + i]);
        mt = fmaxf(mt, partials[4 * B + i]);
    }
    for (int off = 32; off > 0; off >>= 1) {
        sp2 += __shfl_down(sp2, off);
        st2 += __shfl_down(st2, off);
        spt += __shfl_down(spt, off);
        mp = fmaxf(mp, __shfl_down(mp, off));
        mt = fmaxf(mt, __shfl_down(mt, off));
    }
    int wave = t >> 6, lane = t & 63;
    if (lane == 0) {
        reds[wave][0] = sp2; reds[wave][1] = st2; reds[wave][2] = spt;
        redx[wave][0] = mp;  redx[wave][1] = mt;
    }
    __syncthreads();
    if (t == 0) {
        for (int w = 1; w < 16; ++w) {
            sp2 += reds[w][0];
            st2 += reds[w][1];
            spt += reds[w][2];
            mp = fmaxf(mp, redx[w][0]);
            mt = fmaxf(mt, redx[w][1]);
        }
        double Mp = (double)mp, Mt = (double)mt;
        double loss = (sp2 * (Mt / Mp) + st2 * (Mp / Mt) - 2.0 * spt) / sqrt(sp2 * st2);
        out[0] = (float)loss;
    }
}

extern "C" void kernel_launch(void* const* d_in, const int* in_sizes, int n_in,
                              void* d_out, int out_size, void* d_ws, size_t ws_size,
                              hipStream_t stream) {
    const float* output  = (const float*)d_in[0];
    const float* targets = (const float*)d_in[1];
    int B = in_sizes[0] / (NS * 3);
    float* partials = (float*)d_ws;     // 5*B floats

    loss_main<<<B, 256, 0, stream>>>(output, targets, partials, B);
    finalize_loss<<<1, 1024, 0, stream>>>(partials, (float*)d_out, B);
}